// Round 18
// baseline (762.705 us; speedup 1.0000x reference)
//
#include <hip/hip_runtime.h>

#define N_NODES 100000
#define IN_DIM 64
#define EMB 128
#define N_EDGES 1600000
#define BN_EPS 1e-5f

// dst-bucket partition: 782 buckets x 128 nodes
#define NB2    782
#define BNODES 128
#define BCAP2  2560               // mean 2048 + 11 sigma
#define FA_THREADS 512
#define FA_EPT 16
#define FA_BLK (FA_THREADS * FA_EPT)            // 8192
#define FA_GRID ((N_EDGES + FA_BLK - 1) / FA_BLK)   // 196

// ---- workspace layout (bytes) ----
#define WS_GSUM  0
#define WS_GSUM2 512
#define WS_BCUR  1024                       // 782*4 = 3128
#define WS_AGG   8192                       // 25.6 MB
#define WS_SWARR (8192 + 25600000)          // 782*2560*8 = 16,015,360
#define WS_ZERO_BYTES 8192

typedef _Float16 half8_t __attribute__((ext_vector_type(8)));
typedef float floatx4 __attribute__((ext_vector_type(4)));

// ---------------- fillA: bin edges into 782 dst-buckets, 8B packed records ---
// record: x = src | (dst&127)<<20 ; y = bits(w)
__global__ __launch_bounds__(512) void fillA_kernel(
    const int* __restrict__ ei, const float* __restrict__ ew,
    int* __restrict__ bcur, uint2* __restrict__ swArr)
{
    __shared__ int cnt[NB2], base[NB2];
    const int tid = threadIdx.x;
    for (int i = tid; i < NB2; i += FA_THREADS) cnt[i] = 0;
    __syncthreads();
    const int e0 = blockIdx.x * FA_BLK;
    int pk[FA_EPT];
    #pragma unroll
    for (int i = 0; i < FA_EPT; ++i) {
        int e = e0 + i * FA_THREADS + tid;
        pk[i] = -1;
        if (e < N_EDGES) {
            int d = ei[N_EDGES + e];
            int b = d >> 7;
            int pos = atomicAdd(&cnt[b], 1);   // LDS atomic; pos < 8192
            pk[i] = (b << 13) | pos;
        }
    }
    __syncthreads();
    for (int i = tid; i < NB2; i += FA_THREADS)
        base[i] = atomicAdd(&bcur[i], cnt[i]);
    __syncthreads();
    #pragma unroll
    for (int i = 0; i < FA_EPT; ++i) {
        int e = e0 + i * FA_THREADS + tid;
        if (pk[i] >= 0) {
            int b = pk[i] >> 13, pos = pk[i] & 8191;
            int d = ei[N_EDGES + e];
            uint2 rec;
            rec.x = (unsigned)ei[e] | ((unsigned)(d & 127) << 20);
            rec.y = __float_as_uint(ew[e]);
            swArr[(size_t)b * BCAP2 + base[b] + pos] = rec;
        }
    }
}

// ---------------- aggB: bucket-LDS-accumulate gather (replaces CSR+gather) ---
// Block g: zero 128x64 fp32 tile in LDS; stream segment; random x-row read;
// ds_add_f32 into dst-local row (bank = lane&31, conflict-free); coalesced
// agg writeout. No hist/scan/rowstart/pairs; exactly 1.6M edge-ops.
__global__ __launch_bounds__(256) void aggB_kernel(
    const int* __restrict__ bcur, const uint2* __restrict__ swArr,
    const float* __restrict__ x, float* __restrict__ agg)
{
    __shared__ float acc[BNODES * IN_DIM];   // 32 KB
    const int tid  = threadIdx.x;
    const int lane = tid & 63;
    const int wid  = tid >> 6;      // 0..3
    const int g    = blockIdx.x;

    float4* a4 = (float4*)acc;
    #pragma unroll
    for (int i = 0; i < 8; ++i) a4[i * 256 + tid] = make_float4(0.f, 0.f, 0.f, 0.f);
    __syncthreads();

    const int nE = bcur[g];
    const uint2* __restrict__ seg = swArr + (size_t)g * BCAP2;
    const int chunk = (nE + 3) >> 2;
    const int lo = wid * chunk;
    const int hi = min(lo + chunk, nE);

    int j = lo;
    for (; j + 8 <= hi; j += 8) {
        uint2 r[8];
        #pragma unroll
        for (int k = 0; k < 8; ++k) r[k] = seg[j + k];     // wave-uniform loads
        float v[8];
        #pragma unroll
        for (int k = 0; k < 8; ++k)
            v[k] = x[(size_t)(r[k].x & 0xFFFFFu) * IN_DIM + lane];   // 8 in flight
        #pragma unroll
        for (int k = 0; k < 8; ++k)
            atomicAdd(&acc[(r[k].x >> 20) * IN_DIM + lane],
                      __uint_as_float(r[k].y) * v[k]);
    }
    for (; j < hi; ++j) {
        uint2 rr = seg[j];
        atomicAdd(&acc[(rr.x >> 20) * IN_DIM + lane],
                  __uint_as_float(rr.y) * x[(size_t)(rr.x & 0xFFFFFu) * IN_DIM + lane]);
    }
    __syncthreads();

    #pragma unroll
    for (int i = 0; i < 8; ++i) {
        int idx = i * 256 + tid;             // float4 index, 2048 total
        int node = g * BNODES + (idx >> 4);
        if (node < N_NODES)
            *(float4*)&agg[(size_t)node * IN_DIM + (idx & 15) * 4] = a4[idx];
    }
}

// ---------------- gemv (MFMA): h = (agg + x) @ W1 + b1, + BN partials --------
#define GM_ITERS 5
#define GM_ROWS (32 * GM_ITERS)   // 160 rows/block -> 625 blocks
__global__ __launch_bounds__(256) void gemv_kernel(
    const float* __restrict__ agg,
    const float* __restrict__ x,
    const float* __restrict__ W1,   // [64,128] row-major, fp32
    const float* __restrict__ b1,
    float* __restrict__ h,          // [N,128]
    float* __restrict__ gsum, float* __restrict__ gsum2)
{
    __shared__ _Float16 Ah[32][72];
    __shared__ float redS[EMB], redQ[EMB];

    const int tid  = threadIdx.x;
    const int lane = tid & 63;
    const int wid  = tid >> 6;
    const int rg   = wid >> 1;
    const int ch   = wid & 1;
    const int c0w  = ch * 64;
    const int l15  = lane & 15;
    const int kb   = lane >> 4;

    half8_t Bf[4][2];
    #pragma unroll
    for (int ct = 0; ct < 4; ++ct)
        #pragma unroll
        for (int kc = 0; kc < 2; ++kc)
            #pragma unroll
            for (int i = 0; i < 8; ++i)
                Bf[ct][kc][i] = (_Float16)W1[(kc * 32 + kb * 8 + i) * EMB + ct * 16 + c0w + l15];
    float b1c[4];
    #pragma unroll
    for (int ct = 0; ct < 4; ++ct) b1c[ct] = b1[ct * 16 + c0w + l15];

    if (tid < EMB) { redS[tid] = 0.f; redQ[tid] = 0.f; }

    float sAcc[4] = {0.f, 0.f, 0.f, 0.f};
    float qAcc[4] = {0.f, 0.f, 0.f, 0.f};

    const int r0blk = blockIdx.x * GM_ROWS;
    for (int it = 0; it < GM_ITERS; ++it) {
        const int r0 = r0blk + it * 32;
        __syncthreads();
        #pragma unroll
        for (int i = 0; i < 2; ++i) {
            int j   = i * 256 + tid;
            int row = j >> 4;
            int c4  = (j & 15) * 4;
            float4 av = *(const float4*)&agg[(size_t)(r0 + row) * IN_DIM + c4];
            float4 xv = *(const float4*)&x[(size_t)(r0 + row) * IN_DIM + c4];
            Ah[row][c4 + 0] = (_Float16)(av.x + xv.x);
            Ah[row][c4 + 1] = (_Float16)(av.y + xv.y);
            Ah[row][c4 + 2] = (_Float16)(av.z + xv.z);
            Ah[row][c4 + 3] = (_Float16)(av.w + xv.w);
        }
        __syncthreads();

        floatx4 acc[4];
        #pragma unroll
        for (int ct = 0; ct < 4; ++ct)
            acc[ct] = (floatx4){b1c[ct], b1c[ct], b1c[ct], b1c[ct]};
        #pragma unroll
        for (int kc = 0; kc < 2; ++kc) {
            half8_t af = *(half8_t*)&Ah[rg * 16 + l15][kc * 32 + kb * 8];
            #pragma unroll
            for (int ct = 0; ct < 4; ++ct)
                acc[ct] = __builtin_amdgcn_mfma_f32_16x16x32_f16(af, Bf[ct][kc], acc[ct], 0, 0, 0);
        }

        #pragma unroll
        for (int ct = 0; ct < 4; ++ct) {
            #pragma unroll
            for (int i = 0; i < 4; ++i) {
                int row = r0 + rg * 16 + kb * 4 + i;
                float v = acc[ct][i];
                h[(size_t)row * EMB + c0w + ct * 16 + l15] = v;
                sAcc[ct] += v;
                qAcc[ct] += v * v;
            }
        }
    }

    __syncthreads();
    #pragma unroll
    for (int ct = 0; ct < 4; ++ct) {
        atomicAdd(&redS[c0w + ct * 16 + l15], sAcc[ct]);
        atomicAdd(&redQ[c0w + ct * 16 + l15], qAcc[ct]);
    }
    __syncthreads();
    if (tid < EMB) {
        atomicAdd(&gsum[tid],  redS[tid]);
        atomicAdd(&gsum2[tid], redQ[tid]);
    }
}

// ---------------- out = relu(BN(h)) @ W2 + b2, fp16 MFMA (in-place) --------
#define MR 32
#define M2_ITERS 5
#define M2_ROWS (MR * M2_ITERS)   // 160 rows/block -> 625 blocks

__global__ __launch_bounds__(256) void mlp2_kernel(
    float* __restrict__ hio,
    const float* __restrict__ gsum, const float* __restrict__ gsum2,
    const float* __restrict__ gamma, const float* __restrict__ beta,
    const float* __restrict__ W2,   // [128,128] row-major, fp32
    const float* __restrict__ b2)
{
    __shared__ _Float16 Ph[MR][136];
    __shared__ float abuf[EMB], bbuf[EMB];

    const int tid  = threadIdx.x;
    const int lane = tid & 63;
    const int wid  = tid >> 6;
    const int rg   = wid >> 1;
    const int ch   = wid & 1;
    const int c0w  = ch * 64;
    const int l15  = lane & 15;
    const int kb   = lane >> 4;

    if (tid < EMB) {
        const float invN = 1.0f / (float)N_NODES;
        float mean = gsum[tid] * invN;
        float var  = gsum2[tid] * invN - mean * mean;
        float inv  = rsqrtf(var + BN_EPS);
        float a    = gamma[tid] * inv;
        abuf[tid] = a;
        bbuf[tid] = beta[tid] - mean * a;
    }

    const int bcol = c0w + l15;
    half8_t Bf[4][4];
    #pragma unroll
    for (int ct = 0; ct < 4; ++ct) {
        #pragma unroll
        for (int kc = 0; kc < 4; ++kc) {
            #pragma unroll
            for (int i = 0; i < 8; ++i)
                Bf[ct][kc][i] = (_Float16)W2[(kc * 32 + kb * 8 + i) * EMB + ct * 16 + bcol];
        }
    }
    float b2c[4];
    #pragma unroll
    for (int ct = 0; ct < 4; ++ct) b2c[ct] = b2[ct * 16 + bcol];

    __syncthreads();

    const int r0blk = blockIdx.x * M2_ROWS;
    for (int it = 0; it < M2_ITERS; ++it) {
        const int r0 = r0blk + it * MR;
        #pragma unroll
        for (int i = 0; i < 8; ++i) {
            int j   = i * 256 + tid;
            int row = j >> 6;
            int c2  = (j & 63) * 2;
            const float2 hv = *(const float2*)&hio[(size_t)(r0 + row) * EMB + c2];
            float p0 = fmaxf(hv.x * abuf[c2]     + bbuf[c2],     0.f);
            float p1 = fmaxf(hv.y * abuf[c2 + 1] + bbuf[c2 + 1], 0.f);
            Ph[row][c2]     = (_Float16)p0;
            Ph[row][c2 + 1] = (_Float16)p1;
        }
        __syncthreads();

        floatx4 acc[4];
        #pragma unroll
        for (int ct = 0; ct < 4; ++ct)
            acc[ct] = (floatx4){b2c[ct], b2c[ct], b2c[ct], b2c[ct]};
        #pragma unroll
        for (int kc = 0; kc < 4; ++kc) {
            half8_t af = *(half8_t*)&Ph[rg * 16 + l15][kc * 32 + kb * 8];
            #pragma unroll
            for (int ct = 0; ct < 4; ++ct)
                acc[ct] = __builtin_amdgcn_mfma_f32_16x16x32_f16(af, Bf[ct][kc], acc[ct], 0, 0, 0);
        }
        __syncthreads();

        #pragma unroll
        for (int ct = 0; ct < 4; ++ct) {
            #pragma unroll
            for (int i = 0; i < 4; ++i) {
                int row = r0 + rg * 16 + kb * 4 + i;
                hio[(size_t)row * EMB + c0w + ct * 16 + l15] = acc[ct][i];
            }
        }
    }
}

extern "C" void kernel_launch(void* const* d_in, const int* in_sizes, int n_in,
                              void* d_out, int out_size, void* d_ws, size_t ws_size,
                              hipStream_t stream)
{
    const float* x     = (const float*)d_in[0];
    const int*   ei    = (const int*)d_in[1];   // int32 [2,E]
    const float* ew    = (const float*)d_in[3];
    const float* W1    = (const float*)d_in[4];
    const float* b1    = (const float*)d_in[5];
    const float* gamma = (const float*)d_in[6];
    const float* beta  = (const float*)d_in[7];
    const float* W2    = (const float*)d_in[8];
    const float* b2    = (const float*)d_in[9];

    char* ws = (char*)d_ws;
    float*  gsum   = (float*)(ws + WS_GSUM);
    float*  gsum2  = (float*)(ws + WS_GSUM2);
    int*    bcur   = (int*)(ws + WS_BCUR);
    float*  agg    = (float*)(ws + WS_AGG);
    uint2*  swArr  = (uint2*)(ws + WS_SWARR);
    float*  h      = (float*)d_out;

    hipMemsetAsync(d_ws, 0, WS_ZERO_BYTES, stream);

    fillA_kernel<<<FA_GRID, FA_THREADS, 0, stream>>>(ei, ew, bcur, swArr);
    aggB_kernel<<<NB2, 256, 0, stream>>>(bcur, swArr, x, agg);
    gemv_kernel<<<N_NODES / GM_ROWS, 256, 0, stream>>>(agg, x, W1, b1, h, gsum, gsum2);
    mlp2_kernel<<<N_NODES / M2_ROWS, 256, 0, stream>>>(h, gsum, gsum2, gamma, beta, W2, b2);
}

// Round 19
// 724.506 us; speedup vs baseline: 1.0527x; 1.0527x over previous
//
#include <hip/hip_runtime.h>

#define N_NODES 100000
#define IN_DIM 64
#define EMB 128
#define N_EDGES 1600000
#define BN_EPS 1e-5f

// dst-bucket partition: 1564 buckets x 64 nodes
#define NB2    1564
#define BNODES 64
#define BCAP2  1408               // Poisson mean 1024 + 12 sigma
#define FA_THREADS 512
#define FA_EPT 16
#define FA_BLK (FA_THREADS * FA_EPT)            // 8192
#define FA_GRID ((N_EDGES + FA_BLK - 1) / FA_BLK)   // 196

// ---- workspace layout (bytes) ----
#define WS_GSUM  0
#define WS_GSUM2 512
#define WS_BCUR  1024                       // 1564*4 = 6256
#define WS_AGG   8192                       // 25.6 MB
#define WS_SWARR (8192 + 25600000)          // 1564*1408*8 = 17,616,896
#define WS_ZERO_BYTES 8192

typedef _Float16 half8_t __attribute__((ext_vector_type(8)));
typedef float floatx4 __attribute__((ext_vector_type(4)));

// ---------------- fillA: bin edges into 1564 dst-buckets, 8B packed records --
// record: x = src | (dst&63)<<20 ; y = bits(w)
__global__ __launch_bounds__(512) void fillA_kernel(
    const int* __restrict__ ei, const float* __restrict__ ew,
    int* __restrict__ bcur, uint2* __restrict__ swArr)
{
    __shared__ int cnt[NB2], base[NB2];
    const int tid = threadIdx.x;
    for (int i = tid; i < NB2; i += FA_THREADS) cnt[i] = 0;
    __syncthreads();
    const int e0 = blockIdx.x * FA_BLK;
    int pk[FA_EPT];
    #pragma unroll
    for (int i = 0; i < FA_EPT; ++i) {
        int e = e0 + i * FA_THREADS + tid;
        pk[i] = -1;
        if (e < N_EDGES) {
            int d = ei[N_EDGES + e];
            int b = d >> 6;
            int pos = atomicAdd(&cnt[b], 1);   // LDS atomic; pos < 8192
            pk[i] = (b << 13) | pos;
        }
    }
    __syncthreads();
    for (int i = tid; i < NB2; i += FA_THREADS)
        base[i] = atomicAdd(&bcur[i], cnt[i]);
    __syncthreads();
    #pragma unroll
    for (int i = 0; i < FA_EPT; ++i) {
        int e = e0 + i * FA_THREADS + tid;
        if (pk[i] >= 0) {
            int b = pk[i] >> 13, pos = pk[i] & 8191;
            int d = ei[N_EDGES + e];
            uint2 rec;
            rec.x = (unsigned)ei[e] | ((unsigned)(d & 63) << 20);
            rec.y = __float_as_uint(ew[e]);
            swArr[(size_t)b * BCAP2 + base[b] + pos] = rec;
        }
    }
}

// ---------------- aggB-v2: bucket-LDS gather with per-lane record loads ------
// r18 post-mortem: wave-uniform 8B record loads serialized (VALUBusy 2.5%).
// v2 uses gather's idiom: per-lane coalesced 64-record load + shfl broadcast,
// 8 x-row loads in flight, then 8 ds_add_f32 (bank=lane&31, conflict-free).
__global__ __launch_bounds__(256) void aggB_kernel(
    const int* __restrict__ bcur, const uint2* __restrict__ swArr,
    const float* __restrict__ x, float* __restrict__ agg)
{
    __shared__ float acc[BNODES * IN_DIM];   // 16 KB
    const int tid  = threadIdx.x;
    const int lane = tid & 63;
    const int wid  = tid >> 6;      // 0..3
    const int g    = blockIdx.x;

    float4* a4 = (float4*)acc;
    #pragma unroll
    for (int i = 0; i < 4; ++i) a4[i * 256 + tid] = make_float4(0.f, 0.f, 0.f, 0.f);
    __syncthreads();

    const int nE = bcur[g];
    const uint2* __restrict__ seg = swArr + (size_t)g * BCAP2;
    const int chunk = (nE + 3) >> 2;
    const int lo = wid * chunk;
    const int hi = min(lo + chunk, nE);

    for (int j0 = lo; j0 < hi; j0 += 64) {
        const int cnt = min(64, hi - j0);
        uint2 rec = (lane < cnt) ? seg[j0 + lane] : make_uint2(0u, 0u);  // w=0 pad
        int   pu = (int)rec.x;
        float pw = __uint_as_float(rec.y);
        const int nch = (cnt + 7) >> 3;
        for (int c = 0; c < nch; ++c) {
            const int base = c * 8;
            int   dl[8];
            float vv[8];
            #pragma unroll
            for (int t = 0; t < 8; ++t) {
                int   u = __shfl(pu, base + t);
                dl[t] = u >> 20;
                vv[t] = x[(unsigned)((u & 0xFFFFF) * IN_DIM + lane)];   // 8 in flight
            }
            #pragma unroll
            for (int t = 0; t < 8; ++t) {
                float w = __shfl(pw, base + t);
                atomicAdd(&acc[dl[t] * IN_DIM + lane], w * vv[t]);      // ds_add_f32
            }
        }
    }
    __syncthreads();

    #pragma unroll
    for (int i = 0; i < 4; ++i) {
        int idx = i * 256 + tid;             // float4 index, 1024 total
        int node = g * BNODES + (idx >> 4);
        if (node < N_NODES)
            *(float4*)&agg[(size_t)node * IN_DIM + (idx & 15) * 4] = a4[idx];
    }
}

// ---------------- gemv (MFMA): h = (agg + x) @ W1 + b1, + BN partials --------
#define GM_ITERS 5
#define GM_ROWS (32 * GM_ITERS)   // 160 rows/block -> 625 blocks
__global__ __launch_bounds__(256) void gemv_kernel(
    const float* __restrict__ agg,
    const float* __restrict__ x,
    const float* __restrict__ W1,   // [64,128] row-major, fp32
    const float* __restrict__ b1,
    float* __restrict__ h,          // [N,128]
    float* __restrict__ gsum, float* __restrict__ gsum2)
{
    __shared__ _Float16 Ah[32][72];
    __shared__ float redS[EMB], redQ[EMB];

    const int tid  = threadIdx.x;
    const int lane = tid & 63;
    const int wid  = tid >> 6;
    const int rg   = wid >> 1;
    const int ch   = wid & 1;
    const int c0w  = ch * 64;
    const int l15  = lane & 15;
    const int kb   = lane >> 4;

    half8_t Bf[4][2];
    #pragma unroll
    for (int ct = 0; ct < 4; ++ct)
        #pragma unroll
        for (int kc = 0; kc < 2; ++kc)
            #pragma unroll
            for (int i = 0; i < 8; ++i)
                Bf[ct][kc][i] = (_Float16)W1[(kc * 32 + kb * 8 + i) * EMB + ct * 16 + c0w + l15];
    float b1c[4];
    #pragma unroll
    for (int ct = 0; ct < 4; ++ct) b1c[ct] = b1[ct * 16 + c0w + l15];

    if (tid < EMB) { redS[tid] = 0.f; redQ[tid] = 0.f; }

    float sAcc[4] = {0.f, 0.f, 0.f, 0.f};
    float qAcc[4] = {0.f, 0.f, 0.f, 0.f};

    const int r0blk = blockIdx.x * GM_ROWS;
    for (int it = 0; it < GM_ITERS; ++it) {
        const int r0 = r0blk + it * 32;
        __syncthreads();
        #pragma unroll
        for (int i = 0; i < 2; ++i) {
            int j   = i * 256 + tid;
            int row = j >> 4;
            int c4  = (j & 15) * 4;
            float4 av = *(const float4*)&agg[(size_t)(r0 + row) * IN_DIM + c4];
            float4 xv = *(const float4*)&x[(size_t)(r0 + row) * IN_DIM + c4];
            Ah[row][c4 + 0] = (_Float16)(av.x + xv.x);
            Ah[row][c4 + 1] = (_Float16)(av.y + xv.y);
            Ah[row][c4 + 2] = (_Float16)(av.z + xv.z);
            Ah[row][c4 + 3] = (_Float16)(av.w + xv.w);
        }
        __syncthreads();

        floatx4 acc[4];
        #pragma unroll
        for (int ct = 0; ct < 4; ++ct)
            acc[ct] = (floatx4){b1c[ct], b1c[ct], b1c[ct], b1c[ct]};
        #pragma unroll
        for (int kc = 0; kc < 2; ++kc) {
            half8_t af = *(half8_t*)&Ah[rg * 16 + l15][kc * 32 + kb * 8];
            #pragma unroll
            for (int ct = 0; ct < 4; ++ct)
                acc[ct] = __builtin_amdgcn_mfma_f32_16x16x32_f16(af, Bf[ct][kc], acc[ct], 0, 0, 0);
        }

        #pragma unroll
        for (int ct = 0; ct < 4; ++ct) {
            #pragma unroll
            for (int i = 0; i < 4; ++i) {
                int row = r0 + rg * 16 + kb * 4 + i;
                float v = acc[ct][i];
                h[(size_t)row * EMB + c0w + ct * 16 + l15] = v;
                sAcc[ct] += v;
                qAcc[ct] += v * v;
            }
        }
    }

    __syncthreads();
    #pragma unroll
    for (int ct = 0; ct < 4; ++ct) {
        atomicAdd(&redS[c0w + ct * 16 + l15], sAcc[ct]);
        atomicAdd(&redQ[c0w + ct * 16 + l15], qAcc[ct]);
    }
    __syncthreads();
    if (tid < EMB) {
        atomicAdd(&gsum[tid],  redS[tid]);
        atomicAdd(&gsum2[tid], redQ[tid]);
    }
}

// ---------------- out = relu(BN(h)) @ W2 + b2, fp16 MFMA (in-place) --------
#define MR 32
#define M2_ITERS 5
#define M2_ROWS (MR * M2_ITERS)   // 160 rows/block -> 625 blocks

__global__ __launch_bounds__(256) void mlp2_kernel(
    float* __restrict__ hio,
    const float* __restrict__ gsum, const float* __restrict__ gsum2,
    const float* __restrict__ gamma, const float* __restrict__ beta,
    const float* __restrict__ W2,   // [128,128] row-major, fp32
    const float* __restrict__ b2)
{
    __shared__ _Float16 Ph[MR][136];
    __shared__ float abuf[EMB], bbuf[EMB];

    const int tid  = threadIdx.x;
    const int lane = tid & 63;
    const int wid  = tid >> 6;
    const int rg   = wid >> 1;
    const int ch   = wid & 1;
    const int c0w  = ch * 64;
    const int l15  = lane & 15;
    const int kb   = lane >> 4;

    if (tid < EMB) {
        const float invN = 1.0f / (float)N_NODES;
        float mean = gsum[tid] * invN;
        float var  = gsum2[tid] * invN - mean * mean;
        float inv  = rsqrtf(var + BN_EPS);
        float a    = gamma[tid] * inv;
        abuf[tid] = a;
        bbuf[tid] = beta[tid] - mean * a;
    }

    const int bcol = c0w + l15;
    half8_t Bf[4][4];
    #pragma unroll
    for (int ct = 0; ct < 4; ++ct) {
        #pragma unroll
        for (int kc = 0; kc < 4; ++kc) {
            #pragma unroll
            for (int i = 0; i < 8; ++i)
                Bf[ct][kc][i] = (_Float16)W2[(kc * 32 + kb * 8 + i) * EMB + ct * 16 + bcol];
        }
    }
    float b2c[4];
    #pragma unroll
    for (int ct = 0; ct < 4; ++ct) b2c[ct] = b2[ct * 16 + bcol];

    __syncthreads();

    const int r0blk = blockIdx.x * M2_ROWS;
    for (int it = 0; it < M2_ITERS; ++it) {
        const int r0 = r0blk + it * MR;
        #pragma unroll
        for (int i = 0; i < 8; ++i) {
            int j   = i * 256 + tid;
            int row = j >> 6;
            int c2  = (j & 63) * 2;
            const float2 hv = *(const float2*)&hio[(size_t)(r0 + row) * EMB + c2];
            float p0 = fmaxf(hv.x * abuf[c2]     + bbuf[c2],     0.f);
            float p1 = fmaxf(hv.y * abuf[c2 + 1] + bbuf[c2 + 1], 0.f);
            Ph[row][c2]     = (_Float16)p0;
            Ph[row][c2 + 1] = (_Float16)p1;
        }
        __syncthreads();

        floatx4 acc[4];
        #pragma unroll
        for (int ct = 0; ct < 4; ++ct)
            acc[ct] = (floatx4){b2c[ct], b2c[ct], b2c[ct], b2c[ct]};
        #pragma unroll
        for (int kc = 0; kc < 4; ++kc) {
            half8_t af = *(half8_t*)&Ph[rg * 16 + l15][kc * 32 + kb * 8];
            #pragma unroll
            for (int ct = 0; ct < 4; ++ct)
                acc[ct] = __builtin_amdgcn_mfma_f32_16x16x32_f16(af, Bf[ct][kc], acc[ct], 0, 0, 0);
        }
        __syncthreads();

        #pragma unroll
        for (int ct = 0; ct < 4; ++ct) {
            #pragma unroll
            for (int i = 0; i < 4; ++i) {
                int row = r0 + rg * 16 + kb * 4 + i;
                hio[(size_t)row * EMB + c0w + ct * 16 + l15] = acc[ct][i];
            }
        }
    }
}

extern "C" void kernel_launch(void* const* d_in, const int* in_sizes, int n_in,
                              void* d_out, int out_size, void* d_ws, size_t ws_size,
                              hipStream_t stream)
{
    const float* x     = (const float*)d_in[0];
    const int*   ei    = (const int*)d_in[1];   // int32 [2,E]
    const float* ew    = (const float*)d_in[3];
    const float* W1    = (const float*)d_in[4];
    const float* b1    = (const float*)d_in[5];
    const float* gamma = (const float*)d_in[6];
    const float* beta  = (const float*)d_in[7];
    const float* W2    = (const float*)d_in[8];
    const float* b2    = (const float*)d_in[9];

    char* ws = (char*)d_ws;
    float*  gsum   = (float*)(ws + WS_GSUM);
    float*  gsum2  = (float*)(ws + WS_GSUM2);
    int*    bcur   = (int*)(ws + WS_BCUR);
    float*  agg    = (float*)(ws + WS_AGG);
    uint2*  swArr  = (uint2*)(ws + WS_SWARR);
    float*  h      = (float*)d_out;

    hipMemsetAsync(d_ws, 0, WS_ZERO_BYTES, stream);

    fillA_kernel<<<FA_GRID, FA_THREADS, 0, stream>>>(ei, ew, bcur, swArr);
    aggB_kernel<<<NB2, 256, 0, stream>>>(bcur, swArr, x, agg);
    gemv_kernel<<<N_NODES / GM_ROWS, 256, 0, stream>>>(agg, x, W1, b1, h, gsum, gsum2);
    mlp2_kernel<<<N_NODES / M2_ROWS, 256, 0, stream>>>(h, gsum, gsum2, gamma, beta, W2, b2);
}

// Round 20
// 187.153 us; speedup vs baseline: 4.0753x; 3.8712x over previous
//
#include <hip/hip_runtime.h>

#define N_NODES 100000
#define IN_DIM 64
#define EMB 128
#define N_EDGES 1600000
#define BN_EPS 1e-5f

// bucket partition (r17 known-good)
#define NB 98                 // buckets of 1024 dst each
#define BCAP 18432
#define FA_EPT 8
#define FA_BLK 2048
#define FA_GRID ((N_EDGES + FA_BLK - 1) / FA_BLK)   // 782

// ---- workspace layout (bytes) ----
#define WS_ROWSTART 0
#define WS_GSUM     400128
#define WS_GSUM2    400640
#define WS_BCUR     401152
#define WS_PAIRS    802304                  // 12.8 MB
#define WS_AGG      13602304                // 25.6 MB
#define WS_DSTARR   39202304                // 7.2 MB
#define WS_SWARR    46427648                // 14.5 MB
#define WS_ZERO_BYTES 402176

typedef _Float16 half8_t __attribute__((ext_vector_type(8)));
typedef float floatx4 __attribute__((ext_vector_type(4)));

// ---------------- fillA: partition edges into 98 dst-buckets ----------------
__global__ __launch_bounds__(256) void fillA_kernel(
    const int* __restrict__ ei, const float* __restrict__ ew,
    int* __restrict__ bcur, int* __restrict__ dstArr, float2* __restrict__ swArr)
{
    __shared__ int cnt[NB], base[NB];
    const int tid = threadIdx.x;
    if (tid < NB) cnt[tid] = 0;
    __syncthreads();
    const int e0 = blockIdx.x * FA_BLK;
    int pk[FA_EPT];
    #pragma unroll
    for (int i = 0; i < FA_EPT; ++i) {
        int e = e0 + i * 256 + tid;
        pk[i] = -1;
        if (e < N_EDGES) {
            int d = ei[N_EDGES + e];
            int b = d >> 10;
            int pos = atomicAdd(&cnt[b], 1);   // LDS atomic
            pk[i] = (b << 12) | pos;
        }
    }
    __syncthreads();
    if (tid < NB) base[tid] = atomicAdd(&bcur[tid], cnt[tid]);
    __syncthreads();
    #pragma unroll
    for (int i = 0; i < FA_EPT; ++i) {
        int e = e0 + i * 256 + tid;
        if (pk[i] >= 0) {
            int b = pk[i] >> 12, pos = pk[i] & 0xFFF;
            int idx = b * BCAP + base[b] + pos;
            dstArr[idx] = ei[N_EDGES + e];
            swArr[idx]  = make_float2(__int_as_float(ei[e]), ew[e]);
        }
    }
}

// ---------------- fillB2: hist + scan + rowstart + scatter, all in one ------
__global__ __launch_bounds__(1024) void fillB2_kernel(
    const int* __restrict__ bcur, const int* __restrict__ dstArr,
    const float2* __restrict__ swArr,
    int* __restrict__ rowstart, float2* __restrict__ pairs)
{
    __shared__ int cnt2[1024];
    __shared__ int pre[1024];
    __shared__ int sbk[128];
    const int g = blockIdx.x;
    const int tid = threadIdx.x;

    if (tid < 128) sbk[tid] = (tid < NB) ? bcur[tid] : 0;
    cnt2[tid] = 0;
    __syncthreads();
    for (int off = 1; off < 128; off <<= 1) {
        int v = 0;
        if (tid < 128 && tid >= off) v = sbk[tid - off];
        __syncthreads();
        if (tid < 128) sbk[tid] += v;
        __syncthreads();
    }
    const int bucketBase = (g > 0) ? sbk[g - 1] : 0;

    const int nE = bcur[g];
    const int segBase = g * BCAP;
    for (int j = tid; j < nE; j += 1024)
        atomicAdd(&cnt2[dstArr[segBase + j] & 1023], 1);   // LDS atomic (int)
    __syncthreads();

    const int c = cnt2[tid];
    pre[tid] = c;
    __syncthreads();
    for (int off = 1; off < 1024; off <<= 1) {
        int v = (tid >= off) ? pre[tid - off] : 0;
        __syncthreads();
        pre[tid] += v;
        __syncthreads();
    }
    const int start = bucketBase + pre[tid] - c;
    const int node = g * 1024 + tid;
    if (node < N_NODES) rowstart[node] = start;
    if (node == N_NODES - 1) rowstart[N_NODES] = start + c;

    __syncthreads();
    cnt2[tid] = start;
    __syncthreads();
    #pragma unroll 4
    for (int j = tid; j < nE; j += 1024) {
        int d = dstArr[segBase + j];
        int p = atomicAdd(&cnt2[d & 1023], 1);   // LDS atomic (int)
        pairs[p] = swArr[segBase + j];
    }
}

// ---------------- gather v3: e/f float4 lane map (4 edges / wave request) ----
// r15-r17 A/B: time invariant to bytes (fp16 null) and VALU (chunk8 null) ->
// bound by wave-request count. Lane=(e=lane>>4, f=lane&15): one dwordx4
// request covers 4 edges' rows. 8 edges/iter, dual acc, unroll 4.
#define G_NPW 5
__global__ __launch_bounds__(256) void gather_kernel(
    const float* __restrict__ x,
    const int* __restrict__ rowstart,
    const float2* __restrict__ pairs,
    float* __restrict__ agg)
{
    const int tid  = threadIdx.x;
    const int lane = tid & 63;
    const int wid  = tid >> 6;
    const int e    = lane >> 4;     // edge slot 0..3
    const int f    = lane & 15;     // float4 quad 0..15
    const float4* __restrict__ x4 = (const float4*)x;
    const int node0 = (blockIdx.x * 4 + wid) * G_NPW;

    for (int r = 0; r < G_NPW; ++r) {
        const int n  = node0 + r;
        const int jb = rowstart[n];
        const int je = rowstart[n + 1];
        float4 accA = make_float4(0.f, 0.f, 0.f, 0.f);
        float4 accB = make_float4(0.f, 0.f, 0.f, 0.f);
        for (int j0 = jb; j0 < je; j0 += 64) {
            const int cnt = min(64, je - j0);
            float2 p = (lane < cnt) ? pairs[j0 + lane] : make_float2(0.f, 0.f); // src=0,w=0 pad
            int   psrc = __float_as_int(p.x);
            float pw   = p.y;
            const int nch = (cnt + 7) >> 3;     // 8 edges per iter (2 requests)
            #pragma unroll 4
            for (int c = 0; c < nch; ++c) {
                int   uA = __shfl(psrc, c * 8 + e);
                float wA = __shfl(pw,   c * 8 + e);
                int   uB = __shfl(psrc, c * 8 + 4 + e);
                float wB = __shfl(pw,   c * 8 + 4 + e);
                float4 va = x4[(size_t)(unsigned)uA * 16 + f];
                float4 vb = x4[(size_t)(unsigned)uB * 16 + f];
                accA.x += wA * va.x; accA.y += wA * va.y;
                accA.z += wA * va.z; accA.w += wA * va.w;
                accB.x += wB * vb.x; accB.y += wB * vb.y;
                accB.z += wB * vb.z; accB.w += wB * vb.w;
            }
        }
        float4 s = make_float4(accA.x + accB.x, accA.y + accB.y,
                               accA.z + accB.z, accA.w + accB.w);
        // reduce across edge slots (lane bits 4,5)
        s.x += __shfl_xor(s.x, 16); s.y += __shfl_xor(s.y, 16);
        s.z += __shfl_xor(s.z, 16); s.w += __shfl_xor(s.w, 16);
        s.x += __shfl_xor(s.x, 32); s.y += __shfl_xor(s.y, 32);
        s.z += __shfl_xor(s.z, 32); s.w += __shfl_xor(s.w, 32);
        if (e == 0)
            *(float4*)&agg[(size_t)n * IN_DIM + f * 4] = s;   // lanes 0-15: 256B/node
    }
}

// ---------------- gemv (MFMA): h = (agg + x) @ W1 + b1, + BN partials --------
#define GM_ITERS 5
#define GM_ROWS (32 * GM_ITERS)   // 160 rows/block -> 625 blocks
__global__ __launch_bounds__(256) void gemv_kernel(
    const float* __restrict__ agg,
    const float* __restrict__ x,
    const float* __restrict__ W1,   // [64,128] row-major, fp32
    const float* __restrict__ b1,
    float* __restrict__ h,          // [N,128]
    float* __restrict__ gsum, float* __restrict__ gsum2)
{
    __shared__ _Float16 Ah[32][72];
    __shared__ float redS[EMB], redQ[EMB];

    const int tid  = threadIdx.x;
    const int lane = tid & 63;
    const int wid  = tid >> 6;
    const int rg   = wid >> 1;
    const int ch   = wid & 1;
    const int c0w  = ch * 64;
    const int l15  = lane & 15;
    const int kb   = lane >> 4;

    half8_t Bf[4][2];
    #pragma unroll
    for (int ct = 0; ct < 4; ++ct)
        #pragma unroll
        for (int kc = 0; kc < 2; ++kc)
            #pragma unroll
            for (int i = 0; i < 8; ++i)
                Bf[ct][kc][i] = (_Float16)W1[(kc * 32 + kb * 8 + i) * EMB + ct * 16 + c0w + l15];
    float b1c[4];
    #pragma unroll
    for (int ct = 0; ct < 4; ++ct) b1c[ct] = b1[ct * 16 + c0w + l15];

    if (tid < EMB) { redS[tid] = 0.f; redQ[tid] = 0.f; }

    float sAcc[4] = {0.f, 0.f, 0.f, 0.f};
    float qAcc[4] = {0.f, 0.f, 0.f, 0.f};

    const int r0blk = blockIdx.x * GM_ROWS;
    for (int it = 0; it < GM_ITERS; ++it) {
        const int r0 = r0blk + it * 32;
        __syncthreads();
        #pragma unroll
        for (int i = 0; i < 2; ++i) {
            int j   = i * 256 + tid;
            int row = j >> 4;
            int c4  = (j & 15) * 4;
            float4 av = *(const float4*)&agg[(size_t)(r0 + row) * IN_DIM + c4];
            float4 xv = *(const float4*)&x[(size_t)(r0 + row) * IN_DIM + c4];
            Ah[row][c4 + 0] = (_Float16)(av.x + xv.x);
            Ah[row][c4 + 1] = (_Float16)(av.y + xv.y);
            Ah[row][c4 + 2] = (_Float16)(av.z + xv.z);
            Ah[row][c4 + 3] = (_Float16)(av.w + xv.w);
        }
        __syncthreads();

        floatx4 acc[4];
        #pragma unroll
        for (int ct = 0; ct < 4; ++ct)
            acc[ct] = (floatx4){b1c[ct], b1c[ct], b1c[ct], b1c[ct]};
        #pragma unroll
        for (int kc = 0; kc < 2; ++kc) {
            half8_t af = *(half8_t*)&Ah[rg * 16 + l15][kc * 32 + kb * 8];
            #pragma unroll
            for (int ct = 0; ct < 4; ++ct)
                acc[ct] = __builtin_amdgcn_mfma_f32_16x16x32_f16(af, Bf[ct][kc], acc[ct], 0, 0, 0);
        }

        #pragma unroll
        for (int ct = 0; ct < 4; ++ct) {
            #pragma unroll
            for (int i = 0; i < 4; ++i) {
                int row = r0 + rg * 16 + kb * 4 + i;
                float v = acc[ct][i];
                h[(size_t)row * EMB + c0w + ct * 16 + l15] = v;
                sAcc[ct] += v;
                qAcc[ct] += v * v;
            }
        }
    }

    __syncthreads();
    #pragma unroll
    for (int ct = 0; ct < 4; ++ct) {
        atomicAdd(&redS[c0w + ct * 16 + l15], sAcc[ct]);
        atomicAdd(&redQ[c0w + ct * 16 + l15], qAcc[ct]);
    }
    __syncthreads();
    if (tid < EMB) {
        atomicAdd(&gsum[tid],  redS[tid]);
        atomicAdd(&gsum2[tid], redQ[tid]);
    }
}

// ---------------- out = relu(BN(h)) @ W2 + b2, fp16 MFMA (in-place) --------
#define MR 32
#define M2_ITERS 5
#define M2_ROWS (MR * M2_ITERS)   // 160 rows/block -> 625 blocks

__global__ __launch_bounds__(256) void mlp2_kernel(
    float* __restrict__ hio,
    const float* __restrict__ gsum, const float* __restrict__ gsum2,
    const float* __restrict__ gamma, const float* __restrict__ beta,
    const float* __restrict__ W2,   // [128,128] row-major, fp32
    const float* __restrict__ b2)
{
    __shared__ _Float16 Ph[MR][136];
    __shared__ float abuf[EMB], bbuf[EMB];

    const int tid  = threadIdx.x;
    const int lane = tid & 63;
    const int wid  = tid >> 6;
    const int rg   = wid >> 1;
    const int ch   = wid & 1;
    const int c0w  = ch * 64;
    const int l15  = lane & 15;
    const int kb   = lane >> 4;

    if (tid < EMB) {
        const float invN = 1.0f / (float)N_NODES;
        float mean = gsum[tid] * invN;
        float var  = gsum2[tid] * invN - mean * mean;
        float inv  = rsqrtf(var + BN_EPS);
        float a    = gamma[tid] * inv;
        abuf[tid] = a;
        bbuf[tid] = beta[tid] - mean * a;
    }

    const int bcol = c0w + l15;
    half8_t Bf[4][4];
    #pragma unroll
    for (int ct = 0; ct < 4; ++ct) {
        #pragma unroll
        for (int kc = 0; kc < 4; ++kc) {
            #pragma unroll
            for (int i = 0; i < 8; ++i)
                Bf[ct][kc][i] = (_Float16)W2[(kc * 32 + kb * 8 + i) * EMB + ct * 16 + bcol];
        }
    }
    float b2c[4];
    #pragma unroll
    for (int ct = 0; ct < 4; ++ct) b2c[ct] = b2[ct * 16 + bcol];

    __syncthreads();

    const int r0blk = blockIdx.x * M2_ROWS;
    for (int it = 0; it < M2_ITERS; ++it) {
        const int r0 = r0blk + it * MR;
        #pragma unroll
        for (int i = 0; i < 8; ++i) {
            int j   = i * 256 + tid;
            int row = j >> 6;
            int c2  = (j & 63) * 2;
            const float2 hv = *(const float2*)&hio[(size_t)(r0 + row) * EMB + c2];
            float p0 = fmaxf(hv.x * abuf[c2]     + bbuf[c2],     0.f);
            float p1 = fmaxf(hv.y * abuf[c2 + 1] + bbuf[c2 + 1], 0.f);
            Ph[row][c2]     = (_Float16)p0;
            Ph[row][c2 + 1] = (_Float16)p1;
        }
        __syncthreads();

        floatx4 acc[4];
        #pragma unroll
        for (int ct = 0; ct < 4; ++ct)
            acc[ct] = (floatx4){b2c[ct], b2c[ct], b2c[ct], b2c[ct]};
        #pragma unroll
        for (int kc = 0; kc < 4; ++kc) {
            half8_t af = *(half8_t*)&Ph[rg * 16 + l15][kc * 32 + kb * 8];
            #pragma unroll
            for (int ct = 0; ct < 4; ++ct)
                acc[ct] = __builtin_amdgcn_mfma_f32_16x16x32_f16(af, Bf[ct][kc], acc[ct], 0, 0, 0);
        }
        __syncthreads();

        #pragma unroll
        for (int ct = 0; ct < 4; ++ct) {
            #pragma unroll
            for (int i = 0; i < 4; ++i) {
                int row = r0 + rg * 16 + kb * 4 + i;
                hio[(size_t)row * EMB + c0w + ct * 16 + l15] = acc[ct][i];
            }
        }
    }
}

extern "C" void kernel_launch(void* const* d_in, const int* in_sizes, int n_in,
                              void* d_out, int out_size, void* d_ws, size_t ws_size,
                              hipStream_t stream)
{
    const float* x     = (const float*)d_in[0];
    const int*   ei    = (const int*)d_in[1];   // int32 [2,E]
    const float* ew    = (const float*)d_in[3];
    const float* W1    = (const float*)d_in[4];
    const float* b1    = (const float*)d_in[5];
    const float* gamma = (const float*)d_in[6];
    const float* beta  = (const float*)d_in[7];
    const float* W2    = (const float*)d_in[8];
    const float* b2    = (const float*)d_in[9];

    char* ws = (char*)d_ws;
    int*    rowstart = (int*)(ws + WS_ROWSTART);
    float*  gsum     = (float*)(ws + WS_GSUM);
    float*  gsum2    = (float*)(ws + WS_GSUM2);
    int*    bcur     = (int*)(ws + WS_BCUR);
    float2* pairs    = (float2*)(ws + WS_PAIRS);
    float*  agg      = (float*)(ws + WS_AGG);
    int*    dstArr   = (int*)(ws + WS_DSTARR);
    float2* swArr    = (float2*)(ws + WS_SWARR);
    float*  h        = (float*)d_out;

    hipMemsetAsync(d_ws, 0, WS_ZERO_BYTES, stream);

    fillA_kernel<<<FA_GRID, 256, 0, stream>>>(ei, ew, bcur, dstArr, swArr);
    fillB2_kernel<<<NB, 1024, 0, stream>>>(bcur, dstArr, swArr, rowstart, pairs);
    gather_kernel<<<N_NODES / (4 * G_NPW), 256, 0, stream>>>(x, rowstart, pairs, agg);
    gemv_kernel<<<N_NODES / GM_ROWS, 256, 0, stream>>>(agg, x, W1, b1, h, gsum, gsum2);
    mlp2_kernel<<<N_NODES / M2_ROWS, 256, 0, stream>>>(h, gsum, gsum2, gamma, beta, W2, b2);
}

// Round 21
// 162.432 us; speedup vs baseline: 4.6955x; 1.1522x over previous
//
#include <hip/hip_runtime.h>

#define N_NODES 100000
#define IN_DIM 64
#define EMB 128
#define N_EDGES 1600000
#define BN_EPS 1e-5f

// bucket partition
#define NB 98                 // buckets of 1024 dst each
#define BCAP 18432
#define FA_THREADS 512
#define FA_EPT 16
#define FA_BLK (FA_THREADS * FA_EPT)                 // 8192 edges/block
#define FA_GRID ((N_EDGES + FA_BLK - 1) / FA_BLK)   // 196

// ---- workspace layout (bytes) ----
#define WS_GSUM     0
#define WS_GSUM2    512
#define WS_BCUR     1024                    // 98*4
#define WS_ROWSTART 2048                    // 400004 -> ends 402052
#define WS_PAIRS    802304                  // 12.8 MB
#define WS_AGG      13602304                // 25.6 MB
#define WS_DSTARR   39202304                // 7.2 MB (dead after fillB2 -> x16 overlay)
#define WS_SWARR    46427648                // 14.5 MB (dead after fillB2)
#define WS_X16      WS_DSTARR               // 12.8 MB fp16 sidecar
#define WS_ZERO_BYTES 2048

typedef _Float16 half8_t __attribute__((ext_vector_type(8)));
typedef _Float16 half4_t __attribute__((ext_vector_type(4)));
typedef float floatx4 __attribute__((ext_vector_type(4)));

// ---------------- fillA: partition edges into 98 dst-buckets ----------------
// 8192 edges/block -> mean run 84 edges (~672 B contiguous) per bucket:
// ~4x fewer partial-line writebacks than the 2048-edge version (r20: 58 us).
__global__ __launch_bounds__(512) void fillA_kernel(
    const int* __restrict__ ei, const float* __restrict__ ew,
    int* __restrict__ bcur, int* __restrict__ dstArr, float2* __restrict__ swArr)
{
    __shared__ int cnt[NB], base[NB];
    const int tid = threadIdx.x;
    if (tid < NB) cnt[tid] = 0;
    __syncthreads();
    const int e0 = blockIdx.x * FA_BLK;
    int pk[FA_EPT];
    #pragma unroll
    for (int i = 0; i < FA_EPT; ++i) {
        int e = e0 + i * FA_THREADS + tid;
        pk[i] = -1;
        if (e < N_EDGES) {
            int d = ei[N_EDGES + e];
            int b = d >> 10;
            int pos = atomicAdd(&cnt[b], 1);   // LDS atomic; pos < 8192 (13 bits)
            pk[i] = (b << 13) | pos;
        }
    }
    __syncthreads();
    if (tid < NB) base[tid] = atomicAdd(&bcur[tid], cnt[tid]);
    __syncthreads();
    #pragma unroll
    for (int i = 0; i < FA_EPT; ++i) {
        int e = e0 + i * FA_THREADS + tid;
        if (pk[i] >= 0) {
            int b = pk[i] >> 13, pos = pk[i] & 8191;
            int idx = b * BCAP + base[b] + pos;
            dstArr[idx] = ei[N_EDGES + e];
            swArr[idx]  = make_float2(__int_as_float(ei[e]), ew[e]);
        }
    }
}

// ---------------- fillB2: hist + scan + rowstart + scatter, all in one ------
__global__ __launch_bounds__(1024) void fillB2_kernel(
    const int* __restrict__ bcur, const int* __restrict__ dstArr,
    const float2* __restrict__ swArr,
    int* __restrict__ rowstart, float2* __restrict__ pairs)
{
    __shared__ int cnt2[1024];
    __shared__ int pre[1024];
    __shared__ int sbk[128];
    const int g = blockIdx.x;
    const int tid = threadIdx.x;

    if (tid < 128) sbk[tid] = (tid < NB) ? bcur[tid] : 0;
    cnt2[tid] = 0;
    __syncthreads();
    for (int off = 1; off < 128; off <<= 1) {
        int v = 0;
        if (tid < 128 && tid >= off) v = sbk[tid - off];
        __syncthreads();
        if (tid < 128) sbk[tid] += v;
        __syncthreads();
    }
    const int bucketBase = (g > 0) ? sbk[g - 1] : 0;

    const int nE = bcur[g];
    const int segBase = g * BCAP;
    for (int j = tid; j < nE; j += 1024)
        atomicAdd(&cnt2[dstArr[segBase + j] & 1023], 1);   // LDS atomic (int)
    __syncthreads();

    const int c = cnt2[tid];
    pre[tid] = c;
    __syncthreads();
    for (int off = 1; off < 1024; off <<= 1) {
        int v = (tid >= off) ? pre[tid - off] : 0;
        __syncthreads();
        pre[tid] += v;
        __syncthreads();
    }
    const int start = bucketBase + pre[tid] - c;
    const int node = g * 1024 + tid;
    if (node < N_NODES) rowstart[node] = start;
    if (node == N_NODES - 1) rowstart[N_NODES] = start + c;

    __syncthreads();
    cnt2[tid] = start;
    __syncthreads();
    #pragma unroll 4
    for (int j = tid; j < nE; j += 1024) {
        int d = dstArr[segBase + j];
        int p = atomicAdd(&cnt2[d & 1023], 1);   // LDS atomic (int)
        pairs[p] = swArr[segBase + j];
    }
}

// ---------------- cvt: x -> fp16 sidecar (after fillB2 frees the region) ----
__global__ __launch_bounds__(256) void cvt_kernel(
    const float4* __restrict__ x4, ushort4* __restrict__ x16)
{
    int i = blockIdx.x * 256 + threadIdx.x;   // 1.6M float4 units
    if (i >= N_NODES * IN_DIM / 4) return;
    float4 v = x4[i];
    ushort4 u;
    _Float16 a = (_Float16)v.x, b = (_Float16)v.y,
             c = (_Float16)v.z, d = (_Float16)v.w;
    u.x = *(unsigned short*)&a; u.y = *(unsigned short*)&b;
    u.z = *(unsigned short*)&c; u.w = *(unsigned short*)&d;
    x16[i] = u;
}

// ---------------- gather v4: e/f lane map on fp16 rows ----------------------
// r20: e/f fp32 gather = 3.2 TB/s, occ 72% -> now BW-bound. fp16 halves bytes
// (128 B/row, one line) and doubles L2-resident fraction. Lane=(e=lane>>4,
// f=lane&15), 8 B/lane -> 4 edge-rows per 512 B request; requests unchanged
// (clean bytes-only A/B vs r20).
#define G_NPW 5
__global__ __launch_bounds__(256) void gather_kernel(
    const _Float16* __restrict__ x16,
    const int* __restrict__ rowstart,
    const float2* __restrict__ pairs,
    float* __restrict__ agg)
{
    const int tid  = threadIdx.x;
    const int lane = tid & 63;
    const int wid  = tid >> 6;
    const int e    = lane >> 4;     // edge slot 0..3
    const int f    = lane & 15;     // half4 quad 0..15
    const half4_t* __restrict__ xv4 = (const half4_t*)x16;
    const int node0 = (blockIdx.x * 4 + wid) * G_NPW;

    for (int r = 0; r < G_NPW; ++r) {
        const int n  = node0 + r;
        const int jb = rowstart[n];
        const int je = rowstart[n + 1];
        float4 accA = make_float4(0.f, 0.f, 0.f, 0.f);
        float4 accB = make_float4(0.f, 0.f, 0.f, 0.f);
        for (int j0 = jb; j0 < je; j0 += 64) {
            const int cnt = min(64, je - j0);
            float2 p = (lane < cnt) ? pairs[j0 + lane] : make_float2(0.f, 0.f); // src=0,w=0 pad
            int   psrc = __float_as_int(p.x);
            float pw   = p.y;
            const int nch = (cnt + 7) >> 3;     // 8 edges per iter (2 requests)
            #pragma unroll 4
            for (int c = 0; c < nch; ++c) {
                int   uA = __shfl(psrc, c * 8 + e);
                float wA = __shfl(pw,   c * 8 + e);
                int   uB = __shfl(psrc, c * 8 + 4 + e);
                float wB = __shfl(pw,   c * 8 + 4 + e);
                half4_t va = xv4[(size_t)(unsigned)uA * 16 + f];
                half4_t vb = xv4[(size_t)(unsigned)uB * 16 + f];
                accA.x += wA * (float)va[0]; accA.y += wA * (float)va[1];
                accA.z += wA * (float)va[2]; accA.w += wA * (float)va[3];
                accB.x += wB * (float)vb[0]; accB.y += wB * (float)vb[1];
                accB.z += wB * (float)vb[2]; accB.w += wB * (float)vb[3];
            }
        }
        float4 s = make_float4(accA.x + accB.x, accA.y + accB.y,
                               accA.z + accB.z, accA.w + accB.w);
        // reduce across edge slots (lane bits 4,5); lane holds feats f*4..f*4+3
        s.x += __shfl_xor(s.x, 16); s.y += __shfl_xor(s.y, 16);
        s.z += __shfl_xor(s.z, 16); s.w += __shfl_xor(s.w, 16);
        s.x += __shfl_xor(s.x, 32); s.y += __shfl_xor(s.y, 32);
        s.z += __shfl_xor(s.z, 32); s.w += __shfl_xor(s.w, 32);
        if (e == 0)
            *(float4*)&agg[(size_t)n * IN_DIM + f * 4] = s;   // lanes 0-15: 256B/node
    }
}

// ---------------- gemv (MFMA): h = (agg + x) @ W1 + b1, + BN partials --------
#define GM_ITERS 5
#define GM_ROWS (32 * GM_ITERS)   // 160 rows/block -> 625 blocks
__global__ __launch_bounds__(256) void gemv_kernel(
    const float* __restrict__ agg,
    const float* __restrict__ x,
    const float* __restrict__ W1,   // [64,128] row-major, fp32
    const float* __restrict__ b1,
    float* __restrict__ h,          // [N,128]
    float* __restrict__ gsum, float* __restrict__ gsum2)
{
    __shared__ _Float16 Ah[32][72];
    __shared__ float redS[EMB], redQ[EMB];

    const int tid  = threadIdx.x;
    const int lane = tid & 63;
    const int wid  = tid >> 6;
    const int rg   = wid >> 1;
    const int ch   = wid & 1;
    const int c0w  = ch * 64;
    const int l15  = lane & 15;
    const int kb   = lane >> 4;

    half8_t Bf[4][2];
    #pragma unroll
    for (int ct = 0; ct < 4; ++ct)
        #pragma unroll
        for (int kc = 0; kc < 2; ++kc)
            #pragma unroll
            for (int i = 0; i < 8; ++i)
                Bf[ct][kc][i] = (_Float16)W1[(kc * 32 + kb * 8 + i) * EMB + ct * 16 + c0w + l15];
    float b1c[4];
    #pragma unroll
    for (int ct = 0; ct < 4; ++ct) b1c[ct] = b1[ct * 16 + c0w + l15];

    if (tid < EMB) { redS[tid] = 0.f; redQ[tid] = 0.f; }

    float sAcc[4] = {0.f, 0.f, 0.f, 0.f};
    float qAcc[4] = {0.f, 0.f, 0.f, 0.f};

    const int r0blk = blockIdx.x * GM_ROWS;
    for (int it = 0; it < GM_ITERS; ++it) {
        const int r0 = r0blk + it * 32;
        __syncthreads();
        #pragma unroll
        for (int i = 0; i < 2; ++i) {
            int j   = i * 256 + tid;
            int row = j >> 4;
            int c4  = (j & 15) * 4;
            float4 av = *(const float4*)&agg[(size_t)(r0 + row) * IN_DIM + c4];
            float4 xv = *(const float4*)&x[(size_t)(r0 + row) * IN_DIM + c4];
            Ah[row][c4 + 0] = (_Float16)(av.x + xv.x);
            Ah[row][c4 + 1] = (_Float16)(av.y + xv.y);
            Ah[row][c4 + 2] = (_Float16)(av.z + xv.z);
            Ah[row][c4 + 3] = (_Float16)(av.w + xv.w);
        }
        __syncthreads();

        floatx4 acc[4];
        #pragma unroll
        for (int ct = 0; ct < 4; ++ct)
            acc[ct] = (floatx4){b1c[ct], b1c[ct], b1c[ct], b1c[ct]};
        #pragma unroll
        for (int kc = 0; kc < 2; ++kc) {
            half8_t af = *(half8_t*)&Ah[rg * 16 + l15][kc * 32 + kb * 8];
            #pragma unroll
            for (int ct = 0; ct < 4; ++ct)
                acc[ct] = __builtin_amdgcn_mfma_f32_16x16x32_f16(af, Bf[ct][kc], acc[ct], 0, 0, 0);
        }

        #pragma unroll
        for (int ct = 0; ct < 4; ++ct) {
            #pragma unroll
            for (int i = 0; i < 4; ++i) {
                int row = r0 + rg * 16 + kb * 4 + i;
                float v = acc[ct][i];
                h[(size_t)row * EMB + c0w + ct * 16 + l15] = v;
                sAcc[ct] += v;
                qAcc[ct] += v * v;
            }
        }
    }

    __syncthreads();
    #pragma unroll
    for (int ct = 0; ct < 4; ++ct) {
        atomicAdd(&redS[c0w + ct * 16 + l15], sAcc[ct]);
        atomicAdd(&redQ[c0w + ct * 16 + l15], qAcc[ct]);
    }
    __syncthreads();
    if (tid < EMB) {
        atomicAdd(&gsum[tid],  redS[tid]);
        atomicAdd(&gsum2[tid], redQ[tid]);
    }
}

// ---------------- out = relu(BN(h)) @ W2 + b2, fp16 MFMA (in-place) --------
#define MR 32
#define M2_ITERS 5
#define M2_ROWS (MR * M2_ITERS)   // 160 rows/block -> 625 blocks

__global__ __launch_bounds__(256) void mlp2_kernel(
    float* __restrict__ hio,
    const float* __restrict__ gsum, const float* __restrict__ gsum2,
    const float* __restrict__ gamma, const float* __restrict__ beta,
    const float* __restrict__ W2,   // [128,128] row-major, fp32
    const float* __restrict__ b2)
{
    __shared__ _Float16 Ph[MR][136];
    __shared__ float abuf[EMB], bbuf[EMB];

    const int tid  = threadIdx.x;
    const int lane = tid & 63;
    const int wid  = tid >> 6;
    const int rg   = wid >> 1;
    const int ch   = wid & 1;
    const int c0w  = ch * 64;
    const int l15  = lane & 15;
    const int kb   = lane >> 4;

    if (tid < EMB) {
        const float invN = 1.0f / (float)N_NODES;
        float mean = gsum[tid] * invN;
        float var  = gsum2[tid] * invN - mean * mean;
        float inv  = rsqrtf(var + BN_EPS);
        float a    = gamma[tid] * inv;
        abuf[tid] = a;
        bbuf[tid] = beta[tid] - mean * a;
    }

    const int bcol = c0w + l15;
    half8_t Bf[4][4];
    #pragma unroll
    for (int ct = 0; ct < 4; ++ct) {
        #pragma unroll
        for (int kc = 0; kc < 4; ++kc) {
            #pragma unroll
            for (int i = 0; i < 8; ++i)
                Bf[ct][kc][i] = (_Float16)W2[(kc * 32 + kb * 8 + i) * EMB + ct * 16 + bcol];
        }
    }
    float b2c[4];
    #pragma unroll
    for (int ct = 0; ct < 4; ++ct) b2c[ct] = b2[ct * 16 + bcol];

    __syncthreads();

    const int r0blk = blockIdx.x * M2_ROWS;
    for (int it = 0; it < M2_ITERS; ++it) {
        const int r0 = r0blk + it * MR;
        #pragma unroll
        for (int i = 0; i < 8; ++i) {
            int j   = i * 256 + tid;
            int row = j >> 6;
            int c2  = (j & 63) * 2;
            const float2 hv = *(const float2*)&hio[(size_t)(r0 + row) * EMB + c2];
            float p0 = fmaxf(hv.x * abuf[c2]     + bbuf[c2],     0.f);
            float p1 = fmaxf(hv.y * abuf[c2 + 1] + bbuf[c2 + 1], 0.f);
            Ph[row][c2]     = (_Float16)p0;
            Ph[row][c2 + 1] = (_Float16)p1;
        }
        __syncthreads();

        floatx4 acc[4];
        #pragma unroll
        for (int ct = 0; ct < 4; ++ct)
            acc[ct] = (floatx4){b2c[ct], b2c[ct], b2c[ct], b2c[ct]};
        #pragma unroll
        for (int kc = 0; kc < 4; ++kc) {
            half8_t af = *(half8_t*)&Ph[rg * 16 + l15][kc * 32 + kb * 8];
            #pragma unroll
            for (int ct = 0; ct < 4; ++ct)
                acc[ct] = __builtin_amdgcn_mfma_f32_16x16x32_f16(af, Bf[ct][kc], acc[ct], 0, 0, 0);
        }
        __syncthreads();

        #pragma unroll
        for (int ct = 0; ct < 4; ++ct) {
            #pragma unroll
            for (int i = 0; i < 4; ++i) {
                int row = r0 + rg * 16 + kb * 4 + i;
                hio[(size_t)row * EMB + c0w + ct * 16 + l15] = acc[ct][i];
            }
        }
    }
}

extern "C" void kernel_launch(void* const* d_in, const int* in_sizes, int n_in,
                              void* d_out, int out_size, void* d_ws, size_t ws_size,
                              hipStream_t stream)
{
    const float* x     = (const float*)d_in[0];
    const int*   ei    = (const int*)d_in[1];   // int32 [2,E]
    const float* ew    = (const float*)d_in[3];
    const float* W1    = (const float*)d_in[4];
    const float* b1    = (const float*)d_in[5];
    const float* gamma = (const float*)d_in[6];
    const float* beta  = (const float*)d_in[7];
    const float* W2    = (const float*)d_in[8];
    const float* b2    = (const float*)d_in[9];

    char* ws = (char*)d_ws;
    float*    gsum     = (float*)(ws + WS_GSUM);
    float*    gsum2    = (float*)(ws + WS_GSUM2);
    int*      bcur     = (int*)(ws + WS_BCUR);
    int*      rowstart = (int*)(ws + WS_ROWSTART);
    float2*   pairs    = (float2*)(ws + WS_PAIRS);
    float*    agg      = (float*)(ws + WS_AGG);
    int*      dstArr   = (int*)(ws + WS_DSTARR);
    float2*   swArr    = (float2*)(ws + WS_SWARR);
    _Float16* x16      = (_Float16*)(ws + WS_X16);   // overlays dstArr (dead after fillB2)
    float*    h        = (float*)d_out;

    hipMemsetAsync(d_ws, 0, WS_ZERO_BYTES, stream);

    fillA_kernel<<<FA_GRID, FA_THREADS, 0, stream>>>(ei, ew, bcur, dstArr, swArr);
    fillB2_kernel<<<NB, 1024, 0, stream>>>(bcur, dstArr, swArr, rowstart, pairs);
    cvt_kernel<<<(N_NODES * IN_DIM / 4 + 255) / 256, 256, 0, stream>>>(
        (const float4*)x, (ushort4*)x16);
    gather_kernel<<<N_NODES / (4 * G_NPW), 256, 0, stream>>>(x16, rowstart, pairs, agg);
    gemv_kernel<<<N_NODES / GM_ROWS, 256, 0, stream>>>(agg, x, W1, b1, h, gsum, gsum2);
    mlp2_kernel<<<N_NODES / M2_ROWS, 256, 0, stream>>>(h, gsum, gsum2, gamma, beta, W2, b2);
}